// Round 9
// baseline (525.933 us; speedup 1.0000x reference)
//
#include <hip/hip_runtime.h>
#include <hip/hip_bf16.h>

typedef __hip_bfloat16 bf16;
typedef __attribute__((ext_vector_type(8))) short short8v;
typedef __attribute__((ext_vector_type(4))) float float4v;

#define NNODES 169
#define NNTOT  338
#define CH     256
#define NH     4
#define NL     3
#define SPAD   176
#define LN_EPS 1e-5f

__device__ __forceinline__ float b2f(bf16 v) { return __bfloat162float(v); }
__device__ __forceinline__ float lrelu(float v) { return fmaxf(v, 0.2f * v); }
__device__ __forceinline__ float ldm(const void* p, size_t i, int isbf) {
    return isbf ? b2f(((const bf16*)p)[i]) : ((const float*)p)[i];
}
__device__ __forceinline__ short f2bf(float f) {   // RNE fp32 -> bf16 bits
    union { float f; unsigned u; } x; x.f = f;
    return (short)((x.u + 0x7FFFu + ((x.u >> 16) & 1u)) >> 16);
}
__device__ __forceinline__ int sniff_bf(const void* lng) {
    return ((((const unsigned*)lng)[0] & 0xFFFFu) == 0x3F80u) ? 1 : 0;
}

// ---------------------------------------------------------------- weight transpose
// WT[n][k] bf16 for all 4 weight families x 3 layers. grid (256,1,12).
__global__ __launch_bounds__(256) void k_wt(
    const void* __restrict__ Wl, const void* __restrict__ Wr,
    const void* __restrict__ W1, const void* __restrict__ W2,
    short* __restrict__ wlT, short* __restrict__ wrT,
    short* __restrict__ w1T, short* __restrict__ w2T,
    const void* __restrict__ lng)
{
    __shared__ float s_t[32][33];
    const int isbf = sniff_bf(lng);
    const int z = blockIdx.z, mat = z & 3, l = z >> 2;
    const void* src; short* dst; int K, N;
    if      (mat == 0) { src = Wl; dst = wlT; K = CH;     N = NH * CH; }
    else if (mat == 1) { src = Wr; dst = wrT; K = CH;     N = NH * CH; }
    else if (mat == 2) { src = W1; dst = w1T; K = CH;     N = 2 * CH;  }
    else               { src = W2; dst = w2T; K = 2 * CH; N = CH;      }
    const int tiles = (K >> 5) * (N >> 5);
    if ((int)blockIdx.x >= tiles) return;
    const int tn = blockIdx.x % (N >> 5), tk = blockIdx.x / (N >> 5);
    const int k0 = tk * 32, n0 = tn * 32;
    const size_t lKN = (size_t)l * K * N;
    const int tx = threadIdx.x & 31, ty = threadIdx.x >> 5;

    for (int r = ty; r < 32; r += 8)
        s_t[r][tx] = ldm(src, lKN + (size_t)(k0 + r) * N + n0 + tx, isbf);
    __syncthreads();
    for (int r = ty; r < 32; r += 8)
        dst[lKN + (size_t)(n0 + r) * K + k0 + tx] = f2bf(s_t[tx][r]);
}

// ---------------------------------------------------------------- MFMA GEMM core
// 64x64 tile, full-K LDS stage (ONE barrier), then KK/32 uninterrupted MFMA
// chunks. A fp32 (or raw bf16) -> bf16 staged; WT[n][k] bf16 pre-transposed.
template<int KK, int ACT, int RES, int XLT>
__device__ __forceinline__ void mfma_gemm(
    short* __restrict__ sA, short* __restrict__ sBT,
    const void* __restrict__ Av, int a_bf,
    const short* __restrict__ WT,
    const void* __restrict__ bv_, size_t oB, int isbf,
    const void* __restrict__ x_res, int r_bf,
    float* __restrict__ out, float* __restrict__ xlT,
    int M, int N, int row0, int col0)
{
    const int STR = KK + 8;                    // shorts; %32dw = 4 -> 2-way banks (free)
    const int tid = threadIdx.x, lane = tid & 63, w = tid >> 6;
    const int r = tid >> 2, q = tid & 3;       // stage: row, k-quarter
    const int kseg = KK / 4, kb0 = q * kseg;
    const int m = lane & 15, kb = (lane >> 4) * 8;
    const int w16 = w * 16;

    {   // ---- stage A (convert to bf16) and B, one pass
        const int gr = row0 + r;
        const int ok = (gr < M);
        if (a_bf) {
            const bf16* ap = (const bf16*)Av + (size_t)gr * KK + kb0;
            #pragma unroll
            for (int j = 0; j < kseg; j += 8) {
                int4 v = ok ? *(const int4*)(ap + j) : make_int4(0, 0, 0, 0);
                *(int4*)&sA[r * STR + kb0 + j] = v;
            }
        } else {
            const float* ap = (const float*)Av + (size_t)gr * KK + kb0;
            #pragma unroll
            for (int j = 0; j < kseg; j += 8) {
                short v8[8];
                if (ok) {
                    const float4 f0 = *(const float4*)(ap + j);
                    const float4 f1 = *(const float4*)(ap + j + 4);
                    v8[0] = f2bf(f0.x); v8[1] = f2bf(f0.y);
                    v8[2] = f2bf(f0.z); v8[3] = f2bf(f0.w);
                    v8[4] = f2bf(f1.x); v8[5] = f2bf(f1.y);
                    v8[6] = f2bf(f1.z); v8[7] = f2bf(f1.w);
                } else {
                    #pragma unroll
                    for (int u = 0; u < 8; u++) v8[u] = 0;
                }
                *(int4*)&sA[r * STR + kb0 + j] = *(int4*)v8;
            }
        }
        const short* bp = WT + (size_t)(col0 + r) * KK + kb0;
        #pragma unroll
        for (int j = 0; j < kseg; j += 8)
            *(int4*)&sBT[r * STR + kb0 + j] = *(const int4*)(bp + j);
    }
    __syncthreads();

    float4v acc[4];
    #pragma unroll
    for (int t = 0; t < 4; t++) acc[t] = (float4v){0.f, 0.f, 0.f, 0.f};

    #pragma unroll
    for (int kc = 0; kc < KK / 32; kc++) {
        const short8v af = *(const short8v*)&sA[(w16 + m) * STR + kc * 32 + kb];
        #pragma unroll
        for (int t = 0; t < 4; t++) {
            const short8v bfv = *(const short8v*)&sBT[(t * 16 + m) * STR + kc * 32 + kb];
            acc[t] = __builtin_amdgcn_mfma_f32_16x16x32_bf16(af, bfv, acc[t], 0, 0, 0);
        }
    }

    const int rq = (lane >> 4) * 4;
    #pragma unroll
    for (int t = 0; t < 4; t++) {
        const int col = col0 + t * 16 + m;
        const float bias_v = ldm(bv_, oB + col, isbf);
        #pragma unroll
        for (int rr = 0; rr < 4; rr++) {
            const int gr = row0 + w16 + rq + rr;
            if (gr >= M) continue;
            float v = acc[t][rr] + bias_v;
            if (ACT) v = fmaxf(v, 0.f);
            if (RES) v += ldm(x_res, (size_t)gr * N + col, r_bf);
            out[(size_t)gr * N + col] = v;
            if (XLT) {
                const int hh = col >> 8, cc = col & 255;
                const int gg = (gr >= NNODES) ? 1 : 0;
                const int ss = gr - gg * NNODES;
                xlT[((size_t)(gg * NH + hh) * CH + cc) * SPAD + ss] = v;
            }
        }
    }
}

// grid (6,16,2): z=0 -> xl (+xlT), z=1 -> xr.  K=256, N=1024.
__global__ __launch_bounds__(256) void k_gemm_lr(
    const void* __restrict__ Av, int israw,
    const short* __restrict__ wlT, const short* __restrict__ wrT, size_t oWT,
    const void* __restrict__ bl, const void* __restrict__ br, size_t oB,
    float* __restrict__ xl, float* __restrict__ xr, float* __restrict__ xlT,
    const void* __restrict__ lng)
{
    __shared__ short sA[64 * 264];
    __shared__ short sBT[64 * 264];
    const int isbf = sniff_bf(lng);
    const int a_bf = israw ? isbf : 0;
    const int row0 = blockIdx.x * 64, col0 = blockIdx.y * 64;
    if (blockIdx.z == 0)
        mfma_gemm<256,0,0,1>(sA, sBT, Av, a_bf, wlT + oWT, bl, oB, isbf,
                             nullptr, 0, xl, xlT, NNTOT, NH * CH, row0, col0);
    else
        mfma_gemm<256,0,0,0>(sA, sBT, Av, a_bf, wrT + oWT, br, oB, isbf,
                             nullptr, 0, xr, nullptr, NNTOT, NH * CH, row0, col0);
}

// grid (6,8): m1 = relu(h_ln @ W1 + b1). K=256, N=512.
__global__ __launch_bounds__(256) void k_mlp1(
    const float* __restrict__ A, const short* __restrict__ w1T, size_t oWT,
    const void* __restrict__ b, size_t oB,
    float* __restrict__ out, const void* __restrict__ lng)
{
    __shared__ short sA[64 * 264];
    __shared__ short sBT[64 * 264];
    const int isbf = sniff_bf(lng);
    mfma_gemm<256,1,0,0>(sA, sBT, A, 0, w1T + oWT, b, oB, isbf, nullptr, 0,
                         out, nullptr, NNTOT, 2 * CH, blockIdx.x * 64, blockIdx.y * 64);
}

// grid (6,4): x_next = x_res + m1 @ W2 + b2. K=512, N=256.
__global__ __launch_bounds__(256) void k_mlp2(
    const float* __restrict__ A, const short* __restrict__ w2T, size_t oWT,
    const void* __restrict__ b, size_t oB,
    const void* __restrict__ x_res, int israw,
    float* __restrict__ out, const void* __restrict__ lng)
{
    __shared__ short sA[64 * 520];
    __shared__ short sBT[64 * 520];
    const int isbf = sniff_bf(lng);
    const int r_bf = israw ? isbf : 0;
    mfma_gemm<512,0,1,0>(sA, sBT, A, 0, w2T + oWT, b, oB, isbf, x_res, r_bf,
                         out, nullptr, NNTOT, CH, blockIdx.x * 64, blockIdx.y * 64);
}

// ---------------------------------------------------------------- logits + softmax
// grid (43, NH, 2): block owns 4 targets for one (g,h). xlT staged to LDS in
// 4 chunks of 64ch x 176src; channel loop all-LDS; softmax fused.
__global__ __launch_bounds__(256) void k_logits_sm(
    const float* __restrict__ xlT, const float* __restrict__ xr,
    const void* __restrict__ att, size_t oA,
    float* __restrict__ alphaR, const void* __restrict__ lng)
{
    __shared__ float s_att[CH];
    __shared__ float s_xr[4 * CH];
    __shared__ float s_tile[64 * SPAD];
    __shared__ float s_log[4 * SPAD];
    const int isbf = sniff_bf(lng);
    const int g = blockIdx.z, h = blockIdx.y, d0 = blockIdx.x * 4;
    const int tid = threadIdx.x, lane = tid & 63, wv = tid >> 6;

    s_att[tid] = ldm(att, oA + h * CH + tid, isbf);
    #pragma unroll
    for (int i = 0; i < 4; i++) {
        const int d = d0 + i;
        s_xr[i * CH + tid] = (d < NNODES)
            ? xr[(size_t)(g * NNODES + d) * (NH * CH) + h * CH + tid] : 0.f;
    }

    float l0 = 0.f, l1 = 0.f, l2 = 0.f, l3 = 0.f;
    const int s = tid;
    const float4* src = (const float4*)(xlT + ((size_t)(g * NH + h) * CH) * SPAD);
    for (int ch = 0; ch < 4; ch++) {
        __syncthreads();
        for (int i = tid; i < 64 * SPAD / 4; i += 256)
            ((float4*)s_tile)[i] = src[ch * (64 * SPAD / 4) + i];
        __syncthreads();
        if (s < NNODES) {
            const int cb = ch * 64;
            #pragma unroll 8
            for (int c = 0; c < 64; c++) {
                const float v = s_tile[c * SPAD + s];
                const float a = s_att[cb + c];
                l0 += a * lrelu(v + s_xr[cb + c]);
                l1 += a * lrelu(v + s_xr[CH + cb + c]);
                l2 += a * lrelu(v + s_xr[2 * CH + cb + c]);
                l3 += a * lrelu(v + s_xr[3 * CH + cb + c]);
            }
        }
    }
    if (s < NNODES) {
        s_log[s] = l0; s_log[SPAD + s] = l1;
        s_log[2 * SPAD + s] = l2; s_log[3 * SPAD + s] = l3;
    }
    __syncthreads();

    {   // wave wv reduces target row wv
        const int d = d0 + wv;
        const float* row = s_log + wv * SPAD;
        const int s0 = lane, s1 = lane + 64, s2 = lane + 128;
        const float v0 = (s0 < NNODES && s0 != d) ? row[s0] : -1e30f;
        const float v1 = (s1 < NNODES && s1 != d) ? row[s1] : -1e30f;
        const float v2 = (s2 < NNODES && s2 != d) ? row[s2] : -1e30f;
        float mx = fmaxf(v0, fmaxf(v1, v2));
        mx = fmaxf(mx, __shfl_xor(mx, 32)); mx = fmaxf(mx, __shfl_xor(mx, 16));
        mx = fmaxf(mx, __shfl_xor(mx, 8));  mx = fmaxf(mx, __shfl_xor(mx, 4));
        mx = fmaxf(mx, __shfl_xor(mx, 2));  mx = fmaxf(mx, __shfl_xor(mx, 1));
        const float e0 = expf(v0 - mx), e1 = expf(v1 - mx), e2 = expf(v2 - mx);
        float z = e0 + e1 + e2;
        z += __shfl_xor(z, 32); z += __shfl_xor(z, 16); z += __shfl_xor(z, 8);
        z += __shfl_xor(z, 4);  z += __shfl_xor(z, 2);  z += __shfl_xor(z, 1);
        const float sc = 0.25f / (z + 1e-16f);     // head-mean folded in
        if (d < NNODES) {
            float* arow = alphaR + ((size_t)(g * NH + h) * NNODES + d) * SPAD;
            if (s0 < NNODES) arow[s0] = e0 * sc;
            if (s1 < NNODES) arow[s1] = e1 * sc;
            if (s2 < NNODES) arow[s2] = e2 * sc;
        }
    }
}

// ---------------------------------------------------------------- aggregate + LN
// grid (43, 2): block owns 4 targets, ALL heads. wave = head; K-loop stages
// xl 16-source chunks; then head-sum + bias + LayerNorm in-block -> h_ln.
__global__ __launch_bounds__(256) void k_aggln(
    const float* __restrict__ alphaR, const float* __restrict__ xl,
    const void* __restrict__ bias, size_t oB,
    const void* __restrict__ ln_g, size_t oG,
    const void* __restrict__ ln_b, size_t oBt,
    float* __restrict__ h_out, const void* __restrict__ lng)
{
    __shared__ float s_alpha[16 * SPAD];   // [h*4+di][s]  11 KB
    __shared__ float s_buf[16 * 1024];     // xl chunk [si][1024]; later part[h][di][256]
    const int isbf = sniff_bf(lng);
    const int g = blockIdx.y, d0 = blockIdx.x * 4;
    const int tid = threadIdx.x, lane = tid & 63, h = tid >> 6;
    const int c4 = lane * 4;

    for (int idx = tid; idx < 16 * SPAD; idx += 256) {
        const int row = idx / SPAD, s = idx - row * SPAD;   // row = hh*4+di
        const int hh = row >> 2, di = row & 3, d = d0 + di;
        s_alpha[idx] = (d < NNODES && s < NNODES)
            ? alphaR[((size_t)(g * NH + hh) * NNODES + d) * SPAD + s] : 0.f;
    }

    float4 A0 = {0,0,0,0}, A1 = {0,0,0,0}, A2 = {0,0,0,0}, A3 = {0,0,0,0};
    for (int s0 = 0; s0 < NNODES; s0 += 16) {
        __syncthreads();
        for (int i = tid; i < 16 * 256; i += 256) {     // i = float4 index
            const int si = i >> 8, cc = (i & 255) * 4;
            const int s = s0 + si;
            *(float4*)&s_buf[si * 1024 + cc] = (s < NNODES)
                ? *(const float4*)(xl + (size_t)(g * NNODES + s) * 1024 + cc)
                : make_float4(0.f, 0.f, 0.f, 0.f);
        }
        __syncthreads();
        const int smax = min(16, NNODES - s0);
        for (int si = 0; si < smax; si++) {
            const float4 xv = *(const float4*)&s_buf[si * 1024 + h * 256 + c4];
            const float a0 = s_alpha[(h * 4 + 0) * SPAD + s0 + si];
            const float a1 = s_alpha[(h * 4 + 1) * SPAD + s0 + si];
            const float a2 = s_alpha[(h * 4 + 2) * SPAD + s0 + si];
            const float a3 = s_alpha[(h * 4 + 3) * SPAD + s0 + si];
            A0.x += a0 * xv.x; A0.y += a0 * xv.y; A0.z += a0 * xv.z; A0.w += a0 * xv.w;
            A1.x += a1 * xv.x; A1.y += a1 * xv.y; A1.z += a1 * xv.z; A1.w += a1 * xv.w;
            A2.x += a2 * xv.x; A2.y += a2 * xv.y; A2.z += a2 * xv.z; A2.w += a2 * xv.w;
            A3.x += a3 * xv.x; A3.y += a3 * xv.y; A3.z += a3 * xv.z; A3.w += a3 * xv.w;
        }
    }
    __syncthreads();
    *(float4*)&s_buf[(h * 4 + 0) * 256 + c4] = A0;   // part[h][di][c]
    *(float4*)&s_buf[(h * 4 + 1) * 256 + c4] = A1;
    *(float4*)&s_buf[(h * 4 + 2) * 256 + c4] = A2;
    *(float4*)&s_buf[(h * 4 + 3) * 256 + c4] = A3;
    __syncthreads();

    {   // wave h finishes target d0+h: head-sum + bias -> LN -> h_out
        const int d = d0 + h;
        if (d < NNODES) {
            float vch[4];
            float s1 = 0.f, s2 = 0.f;
            #pragma unroll
            for (int j = 0; j < 4; j++) {
                const float v = s_buf[(0 * 4 + h) * 256 + c4 + j]
                              + s_buf[(1 * 4 + h) * 256 + c4 + j]
                              + s_buf[(2 * 4 + h) * 256 + c4 + j]
                              + s_buf[(3 * 4 + h) * 256 + c4 + j]
                              + ldm(bias, oB + c4 + j, isbf);
                vch[j] = v; s1 += v; s2 += v * v;
            }
            s1 += __shfl_xor(s1, 32); s2 += __shfl_xor(s2, 32);
            s1 += __shfl_xor(s1, 16); s2 += __shfl_xor(s2, 16);
            s1 += __shfl_xor(s1, 8);  s2 += __shfl_xor(s2, 8);
            s1 += __shfl_xor(s1, 4);  s2 += __shfl_xor(s2, 4);
            s1 += __shfl_xor(s1, 2);  s2 += __shfl_xor(s2, 2);
            s1 += __shfl_xor(s1, 1);  s2 += __shfl_xor(s2, 1);
            const float mu  = s1 * (1.f / CH);
            const float var = s2 * (1.f / CH) - mu * mu;
            const float rs  = rsqrtf(var + LN_EPS);
            float4 o;
            o.x = (vch[0] - mu) * rs * ldm(ln_g, oG + c4 + 0, isbf) + ldm(ln_b, oBt + c4 + 0, isbf);
            o.y = (vch[1] - mu) * rs * ldm(ln_g, oG + c4 + 1, isbf) + ldm(ln_b, oBt + c4 + 1, isbf);
            o.z = (vch[2] - mu) * rs * ldm(ln_g, oG + c4 + 2, isbf) + ldm(ln_b, oBt + c4 + 2, isbf);
            o.w = (vch[3] - mu) * rs * ldm(ln_g, oG + c4 + 3, isbf) + ldm(ln_b, oBt + c4 + 3, isbf);
            *(float4*)(h_out + (size_t)(g * NNODES + d) * CH + c4) = o;
        }
    }
}

// ---------------------------------------------------------------- pool
__global__ __launch_bounds__(256) void k_pool(const float* __restrict__ x,
                                              void* __restrict__ out,
                                              const void* __restrict__ lng) {
    const int isbf = sniff_bf(lng);
    const int g = blockIdx.x, c = threadIdx.x;
    float s = 0.f;
    const float* p = x + (size_t)g * NNODES * CH + c;
    #pragma unroll 8
    for (int n = 0; n < NNODES; n++) s += p[(size_t)n * CH];
    const float v = s * (1.f / NNODES);
    if (isbf) ((bf16*)out)[g * CH + c] = __float2bfloat16(v);
    else      ((float*)out)[g * CH + c] = v;
}

// ---------------------------------------------------------------- launch
extern "C" void kernel_launch(void* const* d_in, const int* in_sizes, int n_in,
                              void* d_out, int out_size, void* d_ws, size_t ws_size,
                              hipStream_t stream)
{
    const void* x_in = d_in[0];
    const void* Wl   = d_in[1];
    const void* bl   = d_in[2];
    const void* Wr   = d_in[3];
    const void* br   = d_in[4];
    const void* att  = d_in[5];
    const void* bias = d_in[6];
    const void* lng  = d_in[7];
    const void* lnb  = d_in[8];
    const void* W1   = d_in[9];
    const void* b1   = d_in[10];
    const void* W2   = d_in[11];
    const void* b2   = d_in[12];

    float* ws     = (float*)d_ws;
    float* xl     = ws;                                      // 338*1024
    float* xr     = xl + (size_t)NNTOT * NH * CH;            // 338*1024
    float* xlT    = xr + (size_t)NNTOT * NH * CH;            // 2*4*256*176
    float* alphaR = xlT + (size_t)2 * NH * CH * SPAD;        // 2*4*169*176
    float* h_ln   = alphaR + (size_t)2 * NH * NNODES * SPAD; // 338*256
    float* m1     = h_ln + (size_t)NNTOT * CH;               // 338*512
    float* xa     = m1 + (size_t)NNTOT * 2 * CH;             // 338*256
    float* xb     = xa + (size_t)NNTOT * CH;                 // 338*256
    short* wlT    = (short*)(xb + (size_t)NNTOT * CH);       // 3*256*1024
    short* wrT    = wlT + (size_t)NL * CH * NH * CH;         // 3*256*1024
    short* w1T    = wrT + (size_t)NL * CH * NH * CH;         // 3*256*512
    short* w2T    = w1T + (size_t)NL * CH * 2 * CH;          // 3*512*256

    const size_t sB  = NH * CH;
    const size_t sA  = NH * CH;
    const size_t sC  = CH;
    const size_t sB1 = 2 * CH;
    const size_t sWT  = (size_t)CH * NH * CH;
    const size_t sW1T = (size_t)CH * 2 * CH;
    const size_t sW2T = (size_t)2 * CH * CH;

    k_wt<<<dim3(256, 1, 12), 256, 0, stream>>>(
        Wl, Wr, W1, W2, wlT, wrT, w1T, w2T, lng);

    const void* x_l[3] = { x_in, xa, xb };
    float*      x_o[3] = { xa, xb, xa };

    for (int l = 0; l < NL; l++) {
        const int israw = (l == 0);
        k_gemm_lr<<<dim3(6, 16, 2), 256, 0, stream>>>(
            x_l[l], israw, wlT, wrT, (size_t)l * sWT,
            bl, br, (size_t)l * sB, xl, xr, xlT, lng);
        k_logits_sm<<<dim3(43, NH, 2), 256, 0, stream>>>(
            xlT, xr, att, (size_t)l * sA, alphaR, lng);
        k_aggln<<<dim3(43, 2), 256, 0, stream>>>(
            alphaR, xl, bias, (size_t)l * sC, lng, (size_t)l * sC,
            lnb, (size_t)l * sC, h_ln, lng);
        k_mlp1<<<dim3(6, 8), 256, 0, stream>>>(
            h_ln, w1T, (size_t)l * sW1T, b1, (size_t)l * sB1, m1, lng);
        k_mlp2<<<dim3(6, 4), 256, 0, stream>>>(
            m1, w2T, (size_t)l * sW2T, b2, (size_t)l * sC,
            x_l[l], israw, x_o[l], lng);
    }

    k_pool<<<dim3(2), 256, 0, stream>>>(xa, d_out, lng);
}

// Round 10
// 321.768 us; speedup vs baseline: 1.6345x; 1.6345x over previous
//
#include <hip/hip_runtime.h>
#include <hip/hip_bf16.h>

typedef __hip_bfloat16 bf16;
typedef __attribute__((ext_vector_type(8))) short short8v;
typedef __attribute__((ext_vector_type(4))) float float4v;

#define NNODES 169
#define NNTOT  338
#define CH     256
#define NH     4
#define NL     3
#define SPAD   176
#define LN_EPS 1e-5f

__device__ __forceinline__ float b2f(bf16 v) { return __bfloat162float(v); }
__device__ __forceinline__ float lrelu(float v) { return fmaxf(v, 0.2f * v); }
__device__ __forceinline__ float ldm(const void* p, size_t i, int isbf) {
    return isbf ? b2f(((const bf16*)p)[i]) : ((const float*)p)[i];
}
__device__ __forceinline__ short f2bf(float f) {   // RNE fp32 -> bf16 bits
    union { float f; unsigned u; } x; x.f = f;
    return (short)((x.u + 0x7FFFu + ((x.u >> 16) & 1u)) >> 16);
}
__device__ __forceinline__ int sniff_bf(const void* lng) {
    return ((((const unsigned*)lng)[0] & 0xFFFFu) == 0x3F80u) ? 1 : 0;
}

// ---------------------------------------------------------------- weight transpose
// WT[n][k] bf16 for all 4 weight families x 3 layers. grid (256,1,12).
__global__ __launch_bounds__(256) void k_wt(
    const void* __restrict__ Wl, const void* __restrict__ Wr,
    const void* __restrict__ W1, const void* __restrict__ W2,
    short* __restrict__ wlT, short* __restrict__ wrT,
    short* __restrict__ w1T, short* __restrict__ w2T,
    const void* __restrict__ lng)
{
    __shared__ float s_t[32][33];
    const int isbf = sniff_bf(lng);
    const int z = blockIdx.z, mat = z & 3, l = z >> 2;
    const void* src; short* dst; int K, N;
    if      (mat == 0) { src = Wl; dst = wlT; K = CH;     N = NH * CH; }
    else if (mat == 1) { src = Wr; dst = wrT; K = CH;     N = NH * CH; }
    else if (mat == 2) { src = W1; dst = w1T; K = CH;     N = 2 * CH;  }
    else               { src = W2; dst = w2T; K = 2 * CH; N = CH;      }
    const int tiles = (K >> 5) * (N >> 5);
    if ((int)blockIdx.x >= tiles) return;
    const int tn = blockIdx.x % (N >> 5), tk = blockIdx.x / (N >> 5);
    const int k0 = tk * 32, n0 = tn * 32;
    const size_t lKN = (size_t)l * K * N;
    const int tx = threadIdx.x & 31, ty = threadIdx.x >> 5;

    for (int r = ty; r < 32; r += 8)
        s_t[r][tx] = ldm(src, lKN + (size_t)(k0 + r) * N + n0 + tx, isbf);
    __syncthreads();
    for (int r = ty; r < 32; r += 8)
        dst[lKN + (size_t)(n0 + r) * K + k0 + tx] = f2bf(s_t[tx][r]);
}

// ---------------------------------------------------------------- MFMA GEMM core
// 64x64 tile, full-K LDS stage (ONE barrier), then KK/32 uninterrupted MFMA
// chunks. A fp32 (or raw bf16) -> bf16 staged; WT[n][k] bf16 pre-transposed.
template<int KK, int ACT, int RES, int XLT>
__device__ __forceinline__ void mfma_gemm(
    short* __restrict__ sA, short* __restrict__ sBT,
    const void* __restrict__ Av, int a_bf,
    const short* __restrict__ WT,
    const void* __restrict__ bv_, size_t oB, int isbf,
    const void* __restrict__ x_res, int r_bf,
    float* __restrict__ out, float* __restrict__ xlT,
    int M, int N, int row0, int col0)
{
    const int STR = KK + 8;                    // shorts; 2-way banks (free)
    const int tid = threadIdx.x, lane = tid & 63, w = tid >> 6;
    const int r = tid >> 2, q = tid & 3;       // stage: row, k-quarter
    const int kseg = KK / 4, kb0 = q * kseg;
    const int m = lane & 15, kb = (lane >> 4) * 8;
    const int w16 = w * 16;

    {   // ---- stage A (convert to bf16) and B, one pass
        const int gr = row0 + r;
        const int ok = (gr < M);
        if (a_bf) {
            const bf16* ap = (const bf16*)Av + (size_t)gr * KK + kb0;
            #pragma unroll
            for (int j = 0; j < kseg; j += 8) {
                int4 v = ok ? *(const int4*)(ap + j) : make_int4(0, 0, 0, 0);
                *(int4*)&sA[r * STR + kb0 + j] = v;
            }
        } else {
            const float* ap = (const float*)Av + (size_t)gr * KK + kb0;
            #pragma unroll
            for (int j = 0; j < kseg; j += 8) {
                short v8[8];
                if (ok) {
                    const float4 f0 = *(const float4*)(ap + j);
                    const float4 f1 = *(const float4*)(ap + j + 4);
                    v8[0] = f2bf(f0.x); v8[1] = f2bf(f0.y);
                    v8[2] = f2bf(f0.z); v8[3] = f2bf(f0.w);
                    v8[4] = f2bf(f1.x); v8[5] = f2bf(f1.y);
                    v8[6] = f2bf(f1.z); v8[7] = f2bf(f1.w);
                } else {
                    #pragma unroll
                    for (int u = 0; u < 8; u++) v8[u] = 0;
                }
                *(int4*)&sA[r * STR + kb0 + j] = *(int4*)v8;
            }
        }
        const short* bp = WT + (size_t)(col0 + r) * KK + kb0;
        #pragma unroll
        for (int j = 0; j < kseg; j += 8)
            *(int4*)&sBT[r * STR + kb0 + j] = *(const int4*)(bp + j);
    }
    __syncthreads();

    float4v acc[4];
    #pragma unroll
    for (int t = 0; t < 4; t++) acc[t] = (float4v){0.f, 0.f, 0.f, 0.f};

    #pragma unroll
    for (int kc = 0; kc < KK / 32; kc++) {
        const short8v af = *(const short8v*)&sA[(w16 + m) * STR + kc * 32 + kb];
        #pragma unroll
        for (int t = 0; t < 4; t++) {
            const short8v bfv = *(const short8v*)&sBT[(t * 16 + m) * STR + kc * 32 + kb];
            acc[t] = __builtin_amdgcn_mfma_f32_16x16x32_bf16(af, bfv, acc[t], 0, 0, 0);
        }
    }

    const int rq = (lane >> 4) * 4;
    #pragma unroll
    for (int t = 0; t < 4; t++) {
        const int col = col0 + t * 16 + m;
        const float bias_v = ldm(bv_, oB + col, isbf);
        #pragma unroll
        for (int rr = 0; rr < 4; rr++) {
            const int gr = row0 + w16 + rq + rr;
            if (gr >= M) continue;
            float v = acc[t][rr] + bias_v;
            if (ACT) v = fmaxf(v, 0.f);
            if (RES) v += ldm(x_res, (size_t)gr * N + col, r_bf);
            out[(size_t)gr * N + col] = v;
            if (XLT) {
                const int hh = col >> 8, cc = col & 255;
                const int gg = (gr >= NNODES) ? 1 : 0;
                const int ss = gr - gg * NNODES;
                xlT[((size_t)(gg * NH + hh) * CH + cc) * SPAD + ss] = v;
            }
        }
    }
}

// grid (6,16,2): z=0 -> xl (+xlT), z=1 -> xr.  K=256, N=1024.
__global__ __launch_bounds__(256) void k_gemm_lr(
    const void* __restrict__ Av, int israw,
    const short* __restrict__ wlT, const short* __restrict__ wrT, size_t oWT,
    const void* __restrict__ bl, const void* __restrict__ br, size_t oB,
    float* __restrict__ xl, float* __restrict__ xr, float* __restrict__ xlT,
    const void* __restrict__ lng)
{
    __shared__ short sA[64 * 264];
    __shared__ short sBT[64 * 264];
    const int isbf = sniff_bf(lng);
    const int a_bf = israw ? isbf : 0;
    const int row0 = blockIdx.x * 64, col0 = blockIdx.y * 64;
    if (blockIdx.z == 0)
        mfma_gemm<256,0,0,1>(sA, sBT, Av, a_bf, wlT + oWT, bl, oB, isbf,
                             nullptr, 0, xl, xlT, NNTOT, NH * CH, row0, col0);
    else
        mfma_gemm<256,0,0,0>(sA, sBT, Av, a_bf, wrT + oWT, br, oB, isbf,
                             nullptr, 0, xr, nullptr, NNTOT, NH * CH, row0, col0);
}

// grid (6,8): m1 = relu(h_ln @ W1 + b1). K=256, N=512.
__global__ __launch_bounds__(256) void k_mlp1(
    const float* __restrict__ A, const short* __restrict__ w1T, size_t oWT,
    const void* __restrict__ b, size_t oB,
    float* __restrict__ out, const void* __restrict__ lng)
{
    __shared__ short sA[64 * 264];
    __shared__ short sBT[64 * 264];
    const int isbf = sniff_bf(lng);
    mfma_gemm<256,1,0,0>(sA, sBT, A, 0, w1T + oWT, b, oB, isbf, nullptr, 0,
                         out, nullptr, NNTOT, 2 * CH, blockIdx.x * 64, blockIdx.y * 64);
}

// grid (6,4): x_next = x_res + m1 @ W2 + b2. K=512, N=256.
__global__ __launch_bounds__(256) void k_mlp2(
    const float* __restrict__ A, const short* __restrict__ w2T, size_t oWT,
    const void* __restrict__ b, size_t oB,
    const void* __restrict__ x_res, int israw,
    float* __restrict__ out, const void* __restrict__ lng)
{
    __shared__ short sA[64 * 520];
    __shared__ short sBT[64 * 520];
    const int isbf = sniff_bf(lng);
    const int r_bf = israw ? isbf : 0;
    mfma_gemm<512,0,1,0>(sA, sBT, A, 0, w2T + oWT, b, oB, isbf, x_res, r_bf,
                         out, nullptr, NNTOT, CH, blockIdx.x * 64, blockIdx.y * 64);
}

// ---------------------------------------------------------------- logits + softmax
// grid (43, NH, 2): block owns 4 targets for one (g,h). xlT staged to LDS in
// 4 chunks of 64ch x 176src; channel loop all-LDS; softmax fused.
__global__ __launch_bounds__(256) void k_logits_sm(
    const float* __restrict__ xlT, const float* __restrict__ xr,
    const void* __restrict__ att, size_t oA,
    float* __restrict__ alphaR, const void* __restrict__ lng)
{
    __shared__ float s_att[CH];
    __shared__ float s_xr[4 * CH];
    __shared__ float s_tile[64 * SPAD];
    __shared__ float s_log[4 * SPAD];
    const int isbf = sniff_bf(lng);
    const int g = blockIdx.z, h = blockIdx.y, d0 = blockIdx.x * 4;
    const int tid = threadIdx.x, lane = tid & 63, wv = tid >> 6;

    s_att[tid] = ldm(att, oA + h * CH + tid, isbf);
    #pragma unroll
    for (int i = 0; i < 4; i++) {
        const int d = d0 + i;
        s_xr[i * CH + tid] = (d < NNODES)
            ? xr[(size_t)(g * NNODES + d) * (NH * CH) + h * CH + tid] : 0.f;
    }

    float l0 = 0.f, l1 = 0.f, l2 = 0.f, l3 = 0.f;
    const int s = tid;
    const float4* src = (const float4*)(xlT + ((size_t)(g * NH + h) * CH) * SPAD);
    for (int ch = 0; ch < 4; ch++) {
        __syncthreads();
        for (int i = tid; i < 64 * SPAD / 4; i += 256)
            ((float4*)s_tile)[i] = src[ch * (64 * SPAD / 4) + i];
        __syncthreads();
        if (s < NNODES) {
            const int cb = ch * 64;
            #pragma unroll 8
            for (int c = 0; c < 64; c++) {
                const float v = s_tile[c * SPAD + s];
                const float a = s_att[cb + c];
                l0 += a * lrelu(v + s_xr[cb + c]);
                l1 += a * lrelu(v + s_xr[CH + cb + c]);
                l2 += a * lrelu(v + s_xr[2 * CH + cb + c]);
                l3 += a * lrelu(v + s_xr[3 * CH + cb + c]);
            }
        }
    }
    if (s < NNODES) {
        s_log[s] = l0; s_log[SPAD + s] = l1;
        s_log[2 * SPAD + s] = l2; s_log[3 * SPAD + s] = l3;
    }
    __syncthreads();

    {   // wave wv reduces target row wv
        const int d = d0 + wv;
        const float* row = s_log + wv * SPAD;
        const int s0 = lane, s1 = lane + 64, s2 = lane + 128;
        const float v0 = (s0 < NNODES && s0 != d) ? row[s0] : -1e30f;
        const float v1 = (s1 < NNODES && s1 != d) ? row[s1] : -1e30f;
        const float v2 = (s2 < NNODES && s2 != d) ? row[s2] : -1e30f;
        float mx = fmaxf(v0, fmaxf(v1, v2));
        mx = fmaxf(mx, __shfl_xor(mx, 32)); mx = fmaxf(mx, __shfl_xor(mx, 16));
        mx = fmaxf(mx, __shfl_xor(mx, 8));  mx = fmaxf(mx, __shfl_xor(mx, 4));
        mx = fmaxf(mx, __shfl_xor(mx, 2));  mx = fmaxf(mx, __shfl_xor(mx, 1));
        const float e0 = expf(v0 - mx), e1 = expf(v1 - mx), e2 = expf(v2 - mx);
        float z = e0 + e1 + e2;
        z += __shfl_xor(z, 32); z += __shfl_xor(z, 16); z += __shfl_xor(z, 8);
        z += __shfl_xor(z, 4);  z += __shfl_xor(z, 2);  z += __shfl_xor(z, 1);
        const float sc = 0.25f / (z + 1e-16f);     // head-mean folded in
        if (d < NNODES) {
            float* arow = alphaR + ((size_t)(g * NH + h) * NNODES + d) * SPAD;
            if (s0 < NNODES) arow[s0] = e0 * sc;
            if (s1 < NNODES) arow[s1] = e1 * sc;
            if (s2 < NNODES) arow[s2] = e2 * sc;
        }
    }
}

// ---------------------------------------------------------------- aggregate as GEMM
// part[h][g*169+d][c] = sum_s alpha[d,s] * xl[s, h*256+c], per (g,h).
// grid (6 d-tiles of 32, 4 c-tiles of 64, 8 gh). K = sources, BK=32.
__global__ __launch_bounds__(256) void k_agg(
    const float* __restrict__ alphaR, const float* __restrict__ xl,
    float* __restrict__ part)
{
    __shared__ float s_a[32 * 33];
    __shared__ float s_x[32 * 64];
    const int gh = blockIdx.z, g = gh >> 2, h = gh & 3;
    const int d0 = blockIdx.x * 32, c0 = blockIdx.y * 64;
    const int tid = threadIdx.x;
    const int dr = (tid >> 4) * 2, cq = (tid & 15) * 4;
    const int sr = tid >> 3, sc4 = (tid & 7) * 4;
    const int xc8 = (tid & 7) * 8;

    float acc[2][4] = {{0.f,0.f,0.f,0.f},{0.f,0.f,0.f,0.f}};

    for (int s0 = 0; s0 < NNODES; s0 += 32) {
        __syncthreads();
        {
            const int d = d0 + sr;
            const float* ap = alphaR + ((size_t)gh * NNODES + d) * SPAD + s0 + sc4;
            const int ok = (d < NNODES);
            s_a[sr * 33 + sc4 + 0] = (ok && s0 + sc4 + 0 < NNODES) ? ap[0] : 0.f;
            s_a[sr * 33 + sc4 + 1] = (ok && s0 + sc4 + 1 < NNODES) ? ap[1] : 0.f;
            s_a[sr * 33 + sc4 + 2] = (ok && s0 + sc4 + 2 < NNODES) ? ap[2] : 0.f;
            s_a[sr * 33 + sc4 + 3] = (ok && s0 + sc4 + 3 < NNODES) ? ap[3] : 0.f;
        }
        {
            const int sg = s0 + sr;
            if (sg < NNODES) {
                const float* xp = xl + (size_t)(g * NNODES + sg) * (NH * CH) + h * CH + c0 + xc8;
                *(float4*)&s_x[sr * 64 + xc8]     = *(const float4*)(xp);
                *(float4*)&s_x[sr * 64 + xc8 + 4] = *(const float4*)(xp + 4);
            } else {
                #pragma unroll
                for (int j = 0; j < 8; j++) s_x[sr * 64 + xc8 + j] = 0.f;
            }
        }
        __syncthreads();
        #pragma unroll
        for (int k = 0; k < 32; k++) {
            const float a0 = s_a[(dr + 0) * 33 + k];
            const float a1 = s_a[(dr + 1) * 33 + k];
            const float4 xv = *(const float4*)&s_x[k * 64 + cq];
            acc[0][0] += a0 * xv.x; acc[0][1] += a0 * xv.y;
            acc[0][2] += a0 * xv.z; acc[0][3] += a0 * xv.w;
            acc[1][0] += a1 * xv.x; acc[1][1] += a1 * xv.y;
            acc[1][2] += a1 * xv.z; acc[1][3] += a1 * xv.w;
        }
    }
    #pragma unroll
    for (int i = 0; i < 2; i++) {
        const int d = d0 + dr + i;
        if (d >= NNODES) continue;
        float4 v;
        v.x = acc[i][0]; v.y = acc[i][1]; v.z = acc[i][2]; v.w = acc[i][3];
        *(float4*)(part + ((size_t)h * NNTOT + g * NNODES + d) * CH + c0 + cq) = v;
    }
}

// ---------------------------------------------------------------- head-sum + LN
__global__ __launch_bounds__(256) void k_ln(
    const float* __restrict__ part,
    const void* __restrict__ bias, size_t oB,
    const void* __restrict__ ln_g, size_t oG,
    const void* __restrict__ ln_b, size_t oBt,
    float* __restrict__ h_out, const void* __restrict__ lng)
{
    __shared__ float s_red[8];
    const int isbf = sniff_bf(lng);
    const int node = blockIdx.x, c = threadIdx.x;
    const int lane = c & 63, wv = c >> 6;

    float vch = part[((size_t)0 * NNTOT + node) * CH + c]
              + part[((size_t)1 * NNTOT + node) * CH + c]
              + part[((size_t)2 * NNTOT + node) * CH + c]
              + part[((size_t)3 * NNTOT + node) * CH + c]
              + ldm(bias, oB + c, isbf);

    float s1 = vch, s2 = vch * vch;
    s1 += __shfl_xor(s1, 32); s2 += __shfl_xor(s2, 32);
    s1 += __shfl_xor(s1, 16); s2 += __shfl_xor(s2, 16);
    s1 += __shfl_xor(s1, 8);  s2 += __shfl_xor(s2, 8);
    s1 += __shfl_xor(s1, 4);  s2 += __shfl_xor(s2, 4);
    s1 += __shfl_xor(s1, 2);  s2 += __shfl_xor(s2, 2);
    s1 += __shfl_xor(s1, 1);  s2 += __shfl_xor(s2, 1);
    if (lane == 0) { s_red[wv] = s1; s_red[4 + wv] = s2; }
    __syncthreads();
    const float S1 = s_red[0] + s_red[1] + s_red[2] + s_red[3];
    const float S2 = s_red[4] + s_red[5] + s_red[6] + s_red[7];
    const float mu  = S1 * (1.f / CH);
    const float var = S2 * (1.f / CH) - mu * mu;
    const float o = (vch - mu) * rsqrtf(var + LN_EPS) * ldm(ln_g, oG + c, isbf)
                  + ldm(ln_b, oBt + c, isbf);
    h_out[(size_t)node * CH + c] = o;
}

// ---------------------------------------------------------------- pool
__global__ __launch_bounds__(256) void k_pool(const float* __restrict__ x,
                                              void* __restrict__ out,
                                              const void* __restrict__ lng) {
    const int isbf = sniff_bf(lng);
    const int g = blockIdx.x, c = threadIdx.x;
    float s = 0.f;
    const float* p = x + (size_t)g * NNODES * CH + c;
    #pragma unroll 8
    for (int n = 0; n < NNODES; n++) s += p[(size_t)n * CH];
    const float v = s * (1.f / NNODES);
    if (isbf) ((bf16*)out)[g * CH + c] = __float2bfloat16(v);
    else      ((float*)out)[g * CH + c] = v;
}

// ---------------------------------------------------------------- launch
extern "C" void kernel_launch(void* const* d_in, const int* in_sizes, int n_in,
                              void* d_out, int out_size, void* d_ws, size_t ws_size,
                              hipStream_t stream)
{
    const void* x_in = d_in[0];
    const void* Wl   = d_in[1];
    const void* bl   = d_in[2];
    const void* Wr   = d_in[3];
    const void* br   = d_in[4];
    const void* att  = d_in[5];
    const void* bias = d_in[6];
    const void* lng  = d_in[7];
    const void* lnb  = d_in[8];
    const void* W1   = d_in[9];
    const void* b1   = d_in[10];
    const void* W2   = d_in[11];
    const void* b2   = d_in[12];

    float* ws     = (float*)d_ws;
    float* xl     = ws;                                      // 338*1024
    float* xr     = xl + (size_t)NNTOT * NH * CH;            // 338*1024
    float* xlT    = xr + (size_t)NNTOT * NH * CH;            // 2*4*256*176
    float* alphaR = xlT + (size_t)2 * NH * CH * SPAD;        // 2*4*169*176
    float* part   = alphaR + (size_t)2 * NH * NNODES * SPAD; // 4*338*256
    float* h_ln   = part + (size_t)NH * NNTOT * CH;          // 338*256
    float* m1     = h_ln + (size_t)NNTOT * CH;               // 338*512
    float* xa     = m1 + (size_t)NNTOT * 2 * CH;             // 338*256
    float* xb     = xa + (size_t)NNTOT * CH;                 // 338*256
    short* wlT    = (short*)(xb + (size_t)NNTOT * CH);       // 3*256*1024
    short* wrT    = wlT + (size_t)NL * CH * NH * CH;         // 3*256*1024
    short* w1T    = wrT + (size_t)NL * CH * NH * CH;         // 3*256*512
    short* w2T    = w1T + (size_t)NL * CH * 2 * CH;          // 3*512*256

    const size_t sB  = NH * CH;
    const size_t sA  = NH * CH;
    const size_t sC  = CH;
    const size_t sB1 = 2 * CH;
    const size_t sWT  = (size_t)CH * NH * CH;
    const size_t sW1T = (size_t)CH * 2 * CH;
    const size_t sW2T = (size_t)2 * CH * CH;

    k_wt<<<dim3(256, 1, 12), 256, 0, stream>>>(
        Wl, Wr, W1, W2, wlT, wrT, w1T, w2T, lng);

    const void* x_l[3] = { x_in, xa, xb };
    float*      x_o[3] = { xa, xb, xa };

    for (int l = 0; l < NL; l++) {
        const int israw = (l == 0);
        k_gemm_lr<<<dim3(6, 16, 2), 256, 0, stream>>>(
            x_l[l], israw, wlT, wrT, (size_t)l * sWT,
            bl, br, (size_t)l * sB, xl, xr, xlT, lng);
        k_logits_sm<<<dim3(43, NH, 2), 256, 0, stream>>>(
            xlT, xr, att, (size_t)l * sA, alphaR, lng);
        k_agg<<<dim3(6, 4, 8), 256, 0, stream>>>(alphaR, xl, part);
        k_ln<<<dim3(NNTOT), 256, 0, stream>>>(
            part, bias, (size_t)l * sC, lng, (size_t)l * sC, lnb, (size_t)l * sC,
            h_ln, lng);
        k_mlp1<<<dim3(6, 8), 256, 0, stream>>>(
            h_ln, w1T, (size_t)l * sW1T, b1, (size_t)l * sB1, m1, lng);
        k_mlp2<<<dim3(6, 4), 256, 0, stream>>>(
            m1, w2T, (size_t)l * sW2T, b2, (size_t)l * sC,
            x_l[l], israw, x_o[l], lng);
    }

    k_pool<<<dim3(2), 256, 0, stream>>>(xa, d_out, lng);
}